// Round 4
// baseline (781.677 us; speedup 1.0000x reference)
//
#include <hip/hip_runtime.h>
#include <hip/hip_bf16.h>

#define NN 50000
#define NE 800000
#define DH 128
#define NGRAPH 512
#define NCLS 10
#define BN_EPS 1e-5f
#define SCAN_NB ((NN + 255) / 256)   // 196
#define AGG_BLOCKS 2048

typedef unsigned int uint;

// ---------------- CSR build ----------------

__global__ void hist_kernel(const int* __restrict__ dst, int* __restrict__ counts, int E) {
    int e = blockIdx.x * blockDim.x + threadIdx.x;
    if (e < E) atomicAdd(&counts[dst[e]], 1);
}

__global__ void compute_dinv_kernel(const int* __restrict__ counts, float* __restrict__ dinv, int N) {
    int n = blockIdx.x * blockDim.x + threadIdx.x;
    if (n < N) dinv[n] = rsqrtf((float)(counts[n] + 1));
}

__launch_bounds__(256)
__global__ void scan1_kernel(const int* __restrict__ counts, int* __restrict__ bsum, int N) {
    __shared__ int ls[256];
    int i = blockIdx.x * 256 + threadIdx.x;
    ls[threadIdx.x] = (i < N) ? counts[i] : 0;
    __syncthreads();
    for (int off = 128; off > 0; off >>= 1) {
        if (threadIdx.x < off) ls[threadIdx.x] += ls[threadIdx.x + off];
        __syncthreads();
    }
    if (threadIdx.x == 0) bsum[blockIdx.x] = ls[0];
}

__launch_bounds__(256)
__global__ void scan2_kernel(int* __restrict__ bsum, int NB) {
    __shared__ int ls[256];
    int tid = threadIdx.x;
    int v = (tid < NB) ? bsum[tid] : 0;
    ls[tid] = v;
    __syncthreads();
    for (int off = 1; off < 256; off <<= 1) {
        int t = (tid >= off) ? ls[tid - off] : 0;
        __syncthreads();
        ls[tid] += t;
        __syncthreads();
    }
    if (tid < NB) bsum[tid] = ls[tid] - v;   // exclusive
}

__launch_bounds__(256)
__global__ void scan3_kernel(const int* __restrict__ counts, const int* __restrict__ boff,
                             int* __restrict__ offsets, int* __restrict__ cursor, int N) {
    __shared__ int ls[256];
    int tid = threadIdx.x;
    int i = blockIdx.x * 256 + tid;
    int v = (i < N) ? counts[i] : 0;
    ls[tid] = v;
    __syncthreads();
    for (int off = 1; off < 256; off <<= 1) {
        int t = (tid >= off) ? ls[tid - off] : 0;
        __syncthreads();
        ls[tid] += t;
        __syncthreads();
    }
    int base = boff[blockIdx.x];
    if (i < N) {
        int ex = base + ls[tid] - v;
        offsets[i] = ex;
        cursor[i] = ex;
        if (i == N - 1) offsets[N] = base + ls[tid];
    }
}

__global__ void fill_kernel(const int* __restrict__ src, const int* __restrict__ dst,
                            int* __restrict__ cursor, int* __restrict__ csr_src, int E) {
    int e = blockIdx.x * blockDim.x + threadIdx.x;
    if (e < E) {
        int d = dst[e];
        int pos = atomicAdd(&cursor[d], 1);
        __builtin_nontemporal_store(src[e], &csr_src[pos]);
    }
}

// ---------------- GEMM: H' = f(X) @ W, rows scaled by dinv, output bf16 ----------------

template<int MODE>
__launch_bounds__(256)
__global__ void gemm_kernel(const float* __restrict__ X, const float* __restrict__ W,
                            const float* __restrict__ bnacc, const float* __restrict__ gamma,
                            const float* __restrict__ beta, const float* __restrict__ dinv,
                            uint* __restrict__ H, int N) {
    __shared__ float ws[DH * DH];     // 64 KB
    __shared__ float xs[32 * DH];     // 16 KB
    int tid = threadIdx.x;
    int q = tid & 31;

    float sc[4], sh[4];
    if (MODE) {
        const float invN = 1.0f / (float)NN;
        #pragma unroll
        for (int j = 0; j < 4; j++) {
            int f = 4 * q + j;
            float mean = bnacc[f] * invN;
            float var = bnacc[128 + f] * invN - mean * mean;
            float s = gamma[f] * rsqrtf(var + BN_EPS);
            sc[j] = s;
            sh[j] = beta[f] - mean * s;
        }
    }

    const float4* W4 = (const float4*)W;
    float4* ws4 = (float4*)ws;
    #pragma unroll
    for (int i = 0; i < DH * DH / 4 / 256; i++) ws4[tid + i * 256] = W4[tid + i * 256];

    int row0 = blockIdx.x * 32;
    const float4* X4 = (const float4*)X;
    float4* xs4 = (float4*)xs;
    #pragma unroll
    for (int i = 0; i < 4; i++) {
        int li = tid + i * 256;
        int lr = li >> 5;
        int r = row0 + lr;
        float4 v = (r < N) ? X4[(size_t)r * 32 + q] : make_float4(0.f, 0.f, 0.f, 0.f);
        if (MODE) {
            v.x = fmaxf(v.x * sc[0] + sh[0], 0.f);
            v.y = fmaxf(v.y * sc[1] + sh[1], 0.f);
            v.z = fmaxf(v.z * sc[2] + sh[2], 0.f);
            v.w = fmaxf(v.w * sc[3] + sh[3], 0.f);
        }
        xs4[li] = v;
    }
    __syncthreads();

    int cg = tid & 31;
    int rg = tid >> 5;
    float acc[4][4];
    #pragma unroll
    for (int a = 0; a < 4; a++)
        #pragma unroll
        for (int b = 0; b < 4; b++) acc[a][b] = 0.f;

    #pragma unroll 8
    for (int k = 0; k < DH; k++) {
        float4 w = ws4[k * 32 + cg];
        #pragma unroll
        for (int rr = 0; rr < 4; rr++) {
            float xv = xs[(rg * 4 + rr) * DH + k];
            acc[rr][0] += xv * w.x;
            acc[rr][1] += xv * w.y;
            acc[rr][2] += xv * w.z;
            acc[rr][3] += xv * w.w;
        }
    }
    #pragma unroll
    for (int rr = 0; rr < 4; rr++) {
        int r = row0 + rg * 4 + rr;
        if (r < N) {
            float dv = dinv[r];
            __hip_bfloat162 p0 = __float22bfloat162_rn(float2{acc[rr][0] * dv, acc[rr][1] * dv});
            __hip_bfloat162 p1 = __float22bfloat162_rn(float2{acc[rr][2] * dv, acc[rr][3] * dv});
            uint2 o;
            o.x = *(uint*)&p0;
            o.y = *(uint*)&p1;
            ((uint2*)(H + (size_t)r * 64))[cg] = o;
        }
    }
}

// ---------------- Aggregation + fused BN stats ----------------
// out[n] = dinv[n]*(sum_e H'[src_e] + H'[n]) + b ; bnacc += per-feature {sum, sumsq}

__device__ __forceinline__ float bf_lo(uint v) { return __uint_as_float(v << 16); }
__device__ __forceinline__ float bf_hi(uint v) { return __uint_as_float(v & 0xffff0000u); }

__launch_bounds__(256)
__global__ void agg_kernel(const uint* __restrict__ H, const int* __restrict__ offsets,
                           const int* __restrict__ csr_src, const float* __restrict__ dinv,
                           const float* __restrict__ bias, float* __restrict__ out,
                           float* __restrict__ bnacc, int N) {
    int wave = threadIdx.x >> 6;
    int lane = threadIdx.x & 63;
    float2 b = ((const float2*)bias)[lane];
    float sx = 0.f, sy = 0.f, sxx = 0.f, syy = 0.f;

    for (int n = blockIdx.x * 4 + wave; n < N; n += AGG_BLOCKS * 4) {
        int beg = offsets[n], end = offsets[n + 1];
        float ax = 0.f, ay = 0.f;
        int e = beg;
        for (; e + 3 < end; e += 4) {
            int s0 = csr_src[e];
            int s1 = csr_src[e + 1];
            int s2 = csr_src[e + 2];
            int s3 = csr_src[e + 3];
            uint v0 = H[(size_t)s0 * 64 + lane];
            uint v1 = H[(size_t)s1 * 64 + lane];
            uint v2 = H[(size_t)s2 * 64 + lane];
            uint v3 = H[(size_t)s3 * 64 + lane];
            ax += bf_lo(v0) + bf_lo(v1) + bf_lo(v2) + bf_lo(v3);
            ay += bf_hi(v0) + bf_hi(v1) + bf_hi(v2) + bf_hi(v3);
        }
        for (; e < end; e++) {
            uint v = H[(size_t)csr_src[e] * 64 + lane];
            ax += bf_lo(v);
            ay += bf_hi(v);
        }
        uint vn = H[(size_t)n * 64 + lane];
        ax += bf_lo(vn);
        ay += bf_hi(vn);
        float dv = dinv[n];
        float ox = ax * dv + b.x;
        float oy = ay * dv + b.y;
        ((float2*)out)[(size_t)n * 64 + lane] = make_float2(ox, oy);
        sx += ox; sy += oy;
        sxx += ox * ox; syy += oy * oy;
    }

    __shared__ float4 red[4][64];
    red[wave][lane] = make_float4(sx, sy, sxx, syy);
    __syncthreads();
    if (wave == 0) {
        float4 a = red[0][lane], b1 = red[1][lane], c = red[2][lane], d = red[3][lane];
        atomicAdd(&bnacc[2 * lane],       a.x + b1.x + c.x + d.x);
        atomicAdd(&bnacc[2 * lane + 1],   a.y + b1.y + c.y + d.y);
        atomicAdd(&bnacc[128 + 2 * lane], a.z + b1.z + c.z + d.z);
        atomicAdd(&bnacc[128 + 2 * lane + 1], a.w + b1.w + c.w + d.w);
    }
}

// ---------------- Pooling with fused BN+ReLU ----------------

__device__ __forceinline__ int lower_bound_dev(const int* __restrict__ a, int n, int key) {
    int lo = 0, hi = n;
    while (lo < hi) {
        int m = (lo + hi) >> 1;
        if (a[m] < key) lo = m + 1; else hi = m;
    }
    return lo;
}

__launch_bounds__(256)
__global__ void pool_kernel(const float* __restrict__ AGG, const int* __restrict__ batch,
                            const float* __restrict__ bnacc, const float* __restrict__ gamma,
                            const float* __restrict__ beta, float* __restrict__ pooled, int N) {
    int g = blockIdx.x;
    __shared__ int sbeg, send;
    if (threadIdx.x == 0) {
        sbeg = lower_bound_dev(batch, N, g);
        send = lower_bound_dev(batch, N, g + 1);
    }
    __syncthreads();
    int beg = sbeg, end = send;
    int f = threadIdx.x & 127;
    int rh = threadIdx.x >> 7;
    const float invN = 1.0f / (float)NN;
    float mean = bnacc[f] * invN;
    float var = bnacc[128 + f] * invN - mean * mean;
    float sc = gamma[f] * rsqrtf(var + BN_EPS);
    float shf = beta[f] - mean * sc;
    float s = 0.f;
    for (int r = beg + rh; r < end; r += 2)
        s += fmaxf(AGG[(size_t)r * DH + f] * sc + shf, 0.f);
    __shared__ float ls[256];
    ls[threadIdx.x] = s;
    __syncthreads();
    if (threadIdx.x < 128) {
        float tot = ls[threadIdx.x] + ls[threadIdx.x + 128];
        float cnt = (float)(end - beg);
        pooled[g * DH + f] = tot / fmaxf(cnt, 1.f);
    }
}

// ---------------- Final linear: out = pooled @ Wl + bl ----------------

__launch_bounds__(256)
__global__ void final_kernel(const float* __restrict__ pooled, const float* __restrict__ Wl,
                             const float* __restrict__ bl, float* __restrict__ out) {
    int gid = blockIdx.x * blockDim.x + threadIdx.x;
    if (gid >= NGRAPH * NCLS) return;
    int g = gid / NCLS, c = gid % NCLS;
    float s = bl[c];
    #pragma unroll 8
    for (int k = 0; k < DH; k++) s += pooled[g * DH + k] * Wl[k * NCLS + c];
    out[gid] = s;
}

// ---------------- Launch ----------------

extern "C" void kernel_launch(void* const* d_in, const int* in_sizes, int n_in,
                              void* d_out, int out_size, void* d_ws, size_t ws_size,
                              hipStream_t stream) {
    const float* x     = (const float*)d_in[0];
    const int*   edges = (const int*)d_in[1];
    const int*   batch = (const int*)d_in[2];
    const float* W1    = (const float*)d_in[3];
    const float* b1    = (const float*)d_in[4];
    const float* g1    = (const float*)d_in[5];
    const float* be1   = (const float*)d_in[6];
    const float* Wc    = (const float*)d_in[7];
    const float* bc    = (const float*)d_in[8];
    const float* gc    = (const float*)d_in[9];
    const float* bec   = (const float*)d_in[10];
    const float* Wl    = (const float*)d_in[11];
    const float* bl    = (const float*)d_in[12];
    float* out = (float*)d_out;

    const int* esrc = edges;
    const int* edst = edges + NE;

    char* w = (char*)d_ws;
    auto alloc = [&](size_t bytes) -> void* {
        void* p = (void*)w;
        w += (bytes + 255) & ~(size_t)255;
        return p;
    };
    int*   counts  = (int*)alloc(NN * 4);
    int*   offsets = (int*)alloc((NN + 1) * 4);
    int*   cursor  = (int*)alloc(NN * 4);
    float* dinv    = (float*)alloc(NN * 4);
    int*   csr_src = (int*)alloc(NE * 4);
    int*   bsum    = (int*)alloc(256 * 4);
    float* bn_acc  = (float*)alloc(4 * 256 * 4);   // per-layer {sum[128], sumsq[128]}
    float* pooled  = (float*)alloc(NGRAPH * DH * 4);
    uint*  H       = (uint*)alloc((size_t)NN * 64 * 4);      // bf16-packed [N,128]
    float* AGG     = (float*)alloc((size_t)NN * DH * 4);

    hipMemsetAsync(counts, 0, NN * 4, stream);
    hipMemsetAsync(bn_acc, 0, 4 * 256 * 4, stream);
    hist_kernel<<<(NE + 255) / 256, 256, 0, stream>>>(edst, counts, NE);
    compute_dinv_kernel<<<(NN + 255) / 256, 256, 0, stream>>>(counts, dinv, NN);
    scan1_kernel<<<SCAN_NB, 256, 0, stream>>>(counts, bsum, NN);
    scan2_kernel<<<1, 256, 0, stream>>>(bsum, SCAN_NB);
    scan3_kernel<<<SCAN_NB, 256, 0, stream>>>(counts, bsum, offsets, cursor, NN);
    fill_kernel<<<(NE + 255) / 256, 256, 0, stream>>>(esrc, edst, cursor, csr_src, NE);

    const float* act = x;
    for (int l = 0; l < 4; l++) {
        const float* Wm  = (l == 0) ? W1 : Wc + (size_t)(l - 1) * DH * DH;
        const float* bm  = (l == 0) ? b1 : bc + (size_t)(l - 1) * DH;
        const float* gp  = (l == 1) ? g1 : gc + (size_t)(l - 2) * DH;
        const float* bep = (l == 1) ? be1 : bec + (size_t)(l - 2) * DH;

        if (l == 0) {
            gemm_kernel<0><<<(NN + 31) / 32, 256, 0, stream>>>(
                act, Wm, nullptr, nullptr, nullptr, dinv, H, NN);
        } else {
            gemm_kernel<1><<<(NN + 31) / 32, 256, 0, stream>>>(
                act, Wm, bn_acc + (size_t)(l - 1) * 256, gp, bep, dinv, H, NN);
        }
        agg_kernel<<<AGG_BLOCKS, 256, 0, stream>>>(H, offsets, csr_src, dinv, bm, AGG,
                                                   bn_acc + (size_t)l * 256, NN);
        act = AGG;
    }

    pool_kernel<<<NGRAPH, 256, 0, stream>>>(AGG, batch, bn_acc + 3 * 256,
                                            gc + 2 * DH, bec + 2 * DH, pooled, NN);
    final_kernel<<<(NGRAPH * NCLS + 255) / 256, 256, 0, stream>>>(pooled, Wl, bl, out);
}

// Round 5
// 543.266 us; speedup vs baseline: 1.4388x; 1.4388x over previous
//
#include <hip/hip_runtime.h>
#include <hip/hip_bf16.h>

#define NN 50000
#define NE 800000
#define DH 128
#define NGRAPH 512
#define NCLS 10
#define BN_EPS 1e-5f
#define SCAN_NB ((NN + 255) / 256)   // 196

typedef unsigned int uint;

// ---------------- CSR build ----------------

__global__ void hist_kernel(const int* __restrict__ dst, int* __restrict__ counts, int E) {
    int e = blockIdx.x * blockDim.x + threadIdx.x;
    if (e < E) atomicAdd(&counts[dst[e]], 1);
}

__global__ void compute_dinv_kernel(const int* __restrict__ counts, float* __restrict__ dinv, int N) {
    int n = blockIdx.x * blockDim.x + threadIdx.x;
    if (n < N) dinv[n] = rsqrtf((float)(counts[n] + 1));
}

__launch_bounds__(256)
__global__ void scan1_kernel(const int* __restrict__ counts, int* __restrict__ bsum, int N) {
    __shared__ int ls[256];
    int i = blockIdx.x * 256 + threadIdx.x;
    ls[threadIdx.x] = (i < N) ? counts[i] : 0;
    __syncthreads();
    for (int off = 128; off > 0; off >>= 1) {
        if (threadIdx.x < off) ls[threadIdx.x] += ls[threadIdx.x + off];
        __syncthreads();
    }
    if (threadIdx.x == 0) bsum[blockIdx.x] = ls[0];
}

__launch_bounds__(256)
__global__ void scan2_kernel(int* __restrict__ bsum, int NB) {
    __shared__ int ls[256];
    int tid = threadIdx.x;
    int v = (tid < NB) ? bsum[tid] : 0;
    ls[tid] = v;
    __syncthreads();
    for (int off = 1; off < 256; off <<= 1) {
        int t = (tid >= off) ? ls[tid - off] : 0;
        __syncthreads();
        ls[tid] += t;
        __syncthreads();
    }
    if (tid < NB) bsum[tid] = ls[tid] - v;   // exclusive
}

__launch_bounds__(256)
__global__ void scan3_kernel(const int* __restrict__ counts, const int* __restrict__ boff,
                             int* __restrict__ offsets, int* __restrict__ cursor, int N) {
    __shared__ int ls[256];
    int tid = threadIdx.x;
    int i = blockIdx.x * 256 + tid;
    int v = (i < N) ? counts[i] : 0;
    ls[tid] = v;
    __syncthreads();
    for (int off = 1; off < 256; off <<= 1) {
        int t = (tid >= off) ? ls[tid - off] : 0;
        __syncthreads();
        ls[tid] += t;
        __syncthreads();
    }
    int base = boff[blockIdx.x];
    if (i < N) {
        int ex = base + ls[tid] - v;
        offsets[i] = ex;
        cursor[i] = ex;
        if (i == N - 1) offsets[N] = base + ls[tid];
    }
}

__global__ void fill_kernel(const int* __restrict__ src, const int* __restrict__ dst,
                            int* __restrict__ cursor, int* __restrict__ csr_src, int E) {
    int e = blockIdx.x * blockDim.x + threadIdx.x;
    if (e < E) {
        int d = dst[e];
        int pos = atomicAdd(&cursor[d], 1);
        __builtin_nontemporal_store(src[e], &csr_src[pos]);
    }
}

// ---------------- GEMM: H' = f(X) @ W, rows scaled by dinv, output bf16 ----------------

template<int MODE>
__launch_bounds__(256)
__global__ void gemm_kernel(const float* __restrict__ X, const float* __restrict__ W,
                            const float* __restrict__ bnacc, const float* __restrict__ gamma,
                            const float* __restrict__ beta, const float* __restrict__ dinv,
                            uint* __restrict__ H, int N) {
    __shared__ float ws[DH * DH];     // 64 KB
    __shared__ float xs[32 * DH];     // 16 KB
    int tid = threadIdx.x;
    int q = tid & 31;

    float sc[4], sh[4];
    if (MODE) {
        const float invN = 1.0f / (float)NN;
        #pragma unroll
        for (int j = 0; j < 4; j++) {
            int f = 4 * q + j;
            float mean = bnacc[f] * invN;
            float var = bnacc[128 + f] * invN - mean * mean;
            float s = gamma[f] * rsqrtf(var + BN_EPS);
            sc[j] = s;
            sh[j] = beta[f] - mean * s;
        }
    }

    const float4* W4 = (const float4*)W;
    float4* ws4 = (float4*)ws;
    #pragma unroll
    for (int i = 0; i < DH * DH / 4 / 256; i++) ws4[tid + i * 256] = W4[tid + i * 256];

    int row0 = blockIdx.x * 32;
    const float4* X4 = (const float4*)X;
    float4* xs4 = (float4*)xs;
    #pragma unroll
    for (int i = 0; i < 4; i++) {
        int li = tid + i * 256;
        int lr = li >> 5;
        int r = row0 + lr;
        float4 v = (r < N) ? X4[(size_t)r * 32 + q] : make_float4(0.f, 0.f, 0.f, 0.f);
        if (MODE) {
            v.x = fmaxf(v.x * sc[0] + sh[0], 0.f);
            v.y = fmaxf(v.y * sc[1] + sh[1], 0.f);
            v.z = fmaxf(v.z * sc[2] + sh[2], 0.f);
            v.w = fmaxf(v.w * sc[3] + sh[3], 0.f);
        }
        xs4[li] = v;
    }
    __syncthreads();

    int cg = tid & 31;
    int rg = tid >> 5;
    float acc[4][4];
    #pragma unroll
    for (int a = 0; a < 4; a++)
        #pragma unroll
        for (int b = 0; b < 4; b++) acc[a][b] = 0.f;

    #pragma unroll 8
    for (int k = 0; k < DH; k++) {
        float4 w = ws4[k * 32 + cg];
        #pragma unroll
        for (int rr = 0; rr < 4; rr++) {
            float xv = xs[(rg * 4 + rr) * DH + k];
            acc[rr][0] += xv * w.x;
            acc[rr][1] += xv * w.y;
            acc[rr][2] += xv * w.z;
            acc[rr][3] += xv * w.w;
        }
    }
    #pragma unroll
    for (int rr = 0; rr < 4; rr++) {
        int r = row0 + rg * 4 + rr;
        if (r < N) {
            float dv = dinv[r];
            __hip_bfloat162 p0 = __float22bfloat162_rn(float2{acc[rr][0] * dv, acc[rr][1] * dv});
            __hip_bfloat162 p1 = __float22bfloat162_rn(float2{acc[rr][2] * dv, acc[rr][3] * dv});
            uint2 o;
            o.x = *(uint*)&p0;
            o.y = *(uint*)&p1;
            ((uint2*)(H + (size_t)r * 64))[cg] = o;
        }
    }
}

// ---------------- Aggregation: out[n] = dinv[n]*(sum_e H'[src_e] + H'[n]) + b ----------------
// One node per wave, independent blocks (no barrier, no persistence).

__device__ __forceinline__ float bf_lo(uint v) { return __uint_as_float(v << 16); }
__device__ __forceinline__ float bf_hi(uint v) { return __uint_as_float(v & 0xffff0000u); }

__launch_bounds__(256)
__global__ void agg_kernel(const uint* __restrict__ H, const int* __restrict__ offsets,
                           const int* __restrict__ csr_src, const float* __restrict__ dinv,
                           const float* __restrict__ bias, float* __restrict__ out, int N) {
    int n = blockIdx.x * 4 + (threadIdx.x >> 6);
    int lane = threadIdx.x & 63;
    if (n >= N) return;
    int beg = offsets[n], end = offsets[n + 1];
    float ax = 0.f, ay = 0.f;
    int e = beg;
    for (; e + 3 < end; e += 4) {
        int s0 = csr_src[e];
        int s1 = csr_src[e + 1];
        int s2 = csr_src[e + 2];
        int s3 = csr_src[e + 3];
        uint v0 = H[(size_t)s0 * 64 + lane];
        uint v1 = H[(size_t)s1 * 64 + lane];
        uint v2 = H[(size_t)s2 * 64 + lane];
        uint v3 = H[(size_t)s3 * 64 + lane];
        ax += bf_lo(v0) + bf_lo(v1) + bf_lo(v2) + bf_lo(v3);
        ay += bf_hi(v0) + bf_hi(v1) + bf_hi(v2) + bf_hi(v3);
    }
    for (; e < end; e++) {
        uint v = H[(size_t)csr_src[e] * 64 + lane];
        ax += bf_lo(v);
        ay += bf_hi(v);
    }
    uint vn = H[(size_t)n * 64 + lane];
    ax += bf_lo(vn);
    ay += bf_hi(vn);
    float dv = dinv[n];
    float2 b = ((const float2*)bias)[lane];
    ((float2*)out)[(size_t)n * 64 + lane] = make_float2(ax * dv + b.x, ay * dv + b.y);
}

// ---------------- BatchNorm stats (sum, sumsq per feature) ----------------

__launch_bounds__(256)
__global__ void bnstats_kernel(const float* __restrict__ A, float* __restrict__ acc, int N) {
    int f = threadIdx.x & 127;
    int rh = threadIdx.x >> 7;
    float s = 0.f, sq = 0.f;
    for (int r = blockIdx.x * 2 + rh; r < N; r += gridDim.x * 2) {
        float v = A[(size_t)r * DH + f];
        s += v;
        sq += v * v;
    }
    __shared__ float ls[256], lq[256];
    ls[threadIdx.x] = s;
    lq[threadIdx.x] = sq;
    __syncthreads();
    if (threadIdx.x < 128) {
        atomicAdd(&acc[f], ls[threadIdx.x] + ls[threadIdx.x + 128]);
        atomicAdd(&acc[128 + f], lq[threadIdx.x] + lq[threadIdx.x + 128]);
    }
}

// ---------------- Pooling with fused BN+ReLU ----------------

__device__ __forceinline__ int lower_bound_dev(const int* __restrict__ a, int n, int key) {
    int lo = 0, hi = n;
    while (lo < hi) {
        int m = (lo + hi) >> 1;
        if (a[m] < key) lo = m + 1; else hi = m;
    }
    return lo;
}

__launch_bounds__(256)
__global__ void pool_kernel(const float* __restrict__ AGG, const int* __restrict__ batch,
                            const float* __restrict__ bnacc, const float* __restrict__ gamma,
                            const float* __restrict__ beta, float* __restrict__ pooled, int N) {
    int g = blockIdx.x;
    __shared__ int sbeg, send;
    if (threadIdx.x == 0) {
        sbeg = lower_bound_dev(batch, N, g);
        send = lower_bound_dev(batch, N, g + 1);
    }
    __syncthreads();
    int beg = sbeg, end = send;
    int f = threadIdx.x & 127;
    int rh = threadIdx.x >> 7;
    const float invN = 1.0f / (float)NN;
    float mean = bnacc[f] * invN;
    float var = bnacc[128 + f] * invN - mean * mean;
    float sc = gamma[f] * rsqrtf(var + BN_EPS);
    float shf = beta[f] - mean * sc;
    float s = 0.f;
    for (int r = beg + rh; r < end; r += 2)
        s += fmaxf(AGG[(size_t)r * DH + f] * sc + shf, 0.f);
    __shared__ float ls[256];
    ls[threadIdx.x] = s;
    __syncthreads();
    if (threadIdx.x < 128) {
        float tot = ls[threadIdx.x] + ls[threadIdx.x + 128];
        float cnt = (float)(end - beg);
        pooled[g * DH + f] = tot / fmaxf(cnt, 1.f);
    }
}

// ---------------- Final linear: out = pooled @ Wl + bl ----------------

__launch_bounds__(256)
__global__ void final_kernel(const float* __restrict__ pooled, const float* __restrict__ Wl,
                             const float* __restrict__ bl, float* __restrict__ out) {
    int gid = blockIdx.x * blockDim.x + threadIdx.x;
    if (gid >= NGRAPH * NCLS) return;
    int g = gid / NCLS, c = gid % NCLS;
    float s = bl[c];
    #pragma unroll 8
    for (int k = 0; k < DH; k++) s += pooled[g * DH + k] * Wl[k * NCLS + c];
    out[gid] = s;
}

// ---------------- Launch ----------------

extern "C" void kernel_launch(void* const* d_in, const int* in_sizes, int n_in,
                              void* d_out, int out_size, void* d_ws, size_t ws_size,
                              hipStream_t stream) {
    const float* x     = (const float*)d_in[0];
    const int*   edges = (const int*)d_in[1];
    const int*   batch = (const int*)d_in[2];
    const float* W1    = (const float*)d_in[3];
    const float* b1    = (const float*)d_in[4];
    const float* g1    = (const float*)d_in[5];
    const float* be1   = (const float*)d_in[6];
    const float* Wc    = (const float*)d_in[7];
    const float* bc    = (const float*)d_in[8];
    const float* gc    = (const float*)d_in[9];
    const float* bec   = (const float*)d_in[10];
    const float* Wl    = (const float*)d_in[11];
    const float* bl    = (const float*)d_in[12];
    float* out = (float*)d_out;

    const int* esrc = edges;
    const int* edst = edges + NE;

    char* w = (char*)d_ws;
    auto alloc = [&](size_t bytes) -> void* {
        void* p = (void*)w;
        w += (bytes + 255) & ~(size_t)255;
        return p;
    };
    int*   counts  = (int*)alloc(NN * 4);
    int*   offsets = (int*)alloc((NN + 1) * 4);
    int*   cursor  = (int*)alloc(NN * 4);
    float* dinv    = (float*)alloc(NN * 4);
    int*   csr_src = (int*)alloc(NE * 4);
    int*   bsum    = (int*)alloc(256 * 4);
    float* bn_acc  = (float*)alloc(4 * 256 * 4);   // per-layer {sum[128], sumsq[128]}
    float* pooled  = (float*)alloc(NGRAPH * DH * 4);
    uint*  H       = (uint*)alloc((size_t)NN * 64 * 4);      // bf16-packed [N,128]
    float* AGG     = (float*)alloc((size_t)NN * DH * 4);

    hipMemsetAsync(counts, 0, NN * 4, stream);
    hipMemsetAsync(bn_acc, 0, 4 * 256 * 4, stream);
    hist_kernel<<<(NE + 255) / 256, 256, 0, stream>>>(edst, counts, NE);
    compute_dinv_kernel<<<(NN + 255) / 256, 256, 0, stream>>>(counts, dinv, NN);
    scan1_kernel<<<SCAN_NB, 256, 0, stream>>>(counts, bsum, NN);
    scan2_kernel<<<1, 256, 0, stream>>>(bsum, SCAN_NB);
    scan3_kernel<<<SCAN_NB, 256, 0, stream>>>(counts, bsum, offsets, cursor, NN);
    fill_kernel<<<(NE + 255) / 256, 256, 0, stream>>>(esrc, edst, cursor, csr_src, NE);

    const float* act = x;
    for (int l = 0; l < 4; l++) {
        const float* Wm  = (l == 0) ? W1 : Wc + (size_t)(l - 1) * DH * DH;
        const float* bm  = (l == 0) ? b1 : bc + (size_t)(l - 1) * DH;
        const float* gp  = (l == 1) ? g1 : gc + (size_t)(l - 2) * DH;
        const float* bep = (l == 1) ? be1 : bec + (size_t)(l - 2) * DH;

        if (l == 0) {
            gemm_kernel<0><<<(NN + 31) / 32, 256, 0, stream>>>(
                act, Wm, nullptr, nullptr, nullptr, dinv, H, NN);
        } else {
            gemm_kernel<1><<<(NN + 31) / 32, 256, 0, stream>>>(
                act, Wm, bn_acc + (size_t)(l - 1) * 256, gp, bep, dinv, H, NN);
        }
        agg_kernel<<<(NN + 3) / 4, 256, 0, stream>>>(H, offsets, csr_src, dinv, bm, AGG, NN);
        bnstats_kernel<<<256, 256, 0, stream>>>(AGG, bn_acc + (size_t)l * 256, NN);
        act = AGG;
    }

    pool_kernel<<<NGRAPH, 256, 0, stream>>>(AGG, batch, bn_acc + 3 * 256,
                                            gc + 2 * DH, bec + 2 * DH, pooled, NN);
    final_kernel<<<(NGRAPH * NCLS + 255) / 256, 256, 0, stream>>>(pooled, Wl, bl, out);
}

// Round 6
// 472.449 us; speedup vs baseline: 1.6545x; 1.1499x over previous
//
#include <hip/hip_runtime.h>
#include <hip/hip_bf16.h>

#define NN 50000
#define NE 800000
#define DH 128
#define NGRAPH 512
#define NCLS 10
#define BN_EPS 1e-5f
#define SCAN_NB ((NN + 255) / 256)   // 196
#define GEMM_NB ((NN + 63) / 64)     // 782

typedef unsigned int uint;
typedef unsigned short ushort;
typedef __attribute__((ext_vector_type(8))) short short8;
typedef __attribute__((ext_vector_type(4))) float f32x4;

__device__ __forceinline__ ushort f2bf(float x) {
    __hip_bfloat16 h = __float2bfloat16(x);
    return *(ushort*)&h;
}

// ---------------- CSR build ----------------

__global__ void hist_kernel(const int* __restrict__ dst, int* __restrict__ counts, int E) {
    int e = blockIdx.x * blockDim.x + threadIdx.x;
    if (e < E) atomicAdd(&counts[dst[e]], 1);
}

__global__ void compute_dinv_kernel(const int* __restrict__ counts, float* __restrict__ dinv, int N) {
    int n = blockIdx.x * blockDim.x + threadIdx.x;
    if (n < N) dinv[n] = rsqrtf((float)(counts[n] + 1));
}

__launch_bounds__(256)
__global__ void scan1_kernel(const int* __restrict__ counts, int* __restrict__ bsum, int N) {
    __shared__ int ls[256];
    int i = blockIdx.x * 256 + threadIdx.x;
    ls[threadIdx.x] = (i < N) ? counts[i] : 0;
    __syncthreads();
    for (int off = 128; off > 0; off >>= 1) {
        if (threadIdx.x < off) ls[threadIdx.x] += ls[threadIdx.x + off];
        __syncthreads();
    }
    if (threadIdx.x == 0) bsum[blockIdx.x] = ls[0];
}

__launch_bounds__(256)
__global__ void scan2_kernel(int* __restrict__ bsum, int NB) {
    __shared__ int ls[256];
    int tid = threadIdx.x;
    int v = (tid < NB) ? bsum[tid] : 0;
    ls[tid] = v;
    __syncthreads();
    for (int off = 1; off < 256; off <<= 1) {
        int t = (tid >= off) ? ls[tid - off] : 0;
        __syncthreads();
        ls[tid] += t;
        __syncthreads();
    }
    if (tid < NB) bsum[tid] = ls[tid] - v;   // exclusive
}

__launch_bounds__(256)
__global__ void scan3_kernel(const int* __restrict__ counts, const int* __restrict__ boff,
                             int* __restrict__ offsets, int* __restrict__ cursor, int N) {
    __shared__ int ls[256];
    int tid = threadIdx.x;
    int i = blockIdx.x * 256 + tid;
    int v = (i < N) ? counts[i] : 0;
    ls[tid] = v;
    __syncthreads();
    for (int off = 1; off < 256; off <<= 1) {
        int t = (tid >= off) ? ls[tid - off] : 0;
        __syncthreads();
        ls[tid] += t;
        __syncthreads();
    }
    int base = boff[blockIdx.x];
    if (i < N) {
        int ex = base + ls[tid] - v;
        offsets[i] = ex;
        cursor[i] = ex;
        if (i == N - 1) offsets[N] = base + ls[tid];
    }
}

__global__ void fill_kernel(const int* __restrict__ src, const int* __restrict__ dst,
                            int* __restrict__ cursor, int* __restrict__ csr_src, int E) {
    int e = blockIdx.x * blockDim.x + threadIdx.x;
    if (e < E) {
        int d = dst[e];
        int pos = atomicAdd(&cursor[d], 1);
        csr_src[pos] = src[e];
    }
}

// ---------------- Weight transpose+convert: WT[l][n][k] = bf16(W_l[k][n]) ----------------
// grid = 4 layers * 16 tiles (4 kt x 4 nt), 256 threads

__launch_bounds__(256)
__global__ void wtrans_kernel(const float* __restrict__ W1, const float* __restrict__ Wc,
                              ushort* __restrict__ WT) {
    int layer = blockIdx.x >> 4;
    int kt = (blockIdx.x >> 2) & 3, nt = blockIdx.x & 3;
    const float* W = (layer == 0) ? W1 : Wc + (size_t)(layer - 1) * DH * DH;
    __shared__ float tile[32][33];
    int t = threadIdx.x;
    int r = t >> 3;
    int c4 = (t & 7) * 4;
    float4 v = *(const float4*)&W[(size_t)(kt * 32 + r) * DH + nt * 32 + c4];
    tile[r][c4 + 0] = v.x; tile[r][c4 + 1] = v.y;
    tile[r][c4 + 2] = v.z; tile[r][c4 + 3] = v.w;
    __syncthreads();
    int n = t >> 3, k4 = (t & 7) * 4;
    ushort4 o;
    o.x = f2bf(tile[k4 + 0][n]);
    o.y = f2bf(tile[k4 + 1][n]);
    o.z = f2bf(tile[k4 + 2][n]);
    o.w = f2bf(tile[k4 + 3][n]);
    *(ushort4*)&WT[(size_t)layer * DH * DH + (size_t)(nt * 32 + n) * DH + kt * 32 + k4] = o;
}

// ---------------- MFMA GEMM: H'[r] = dinv[r] * (f(X[r]) @ W), bf16 out ----------------
// MODE==0: X raw. MODE==1: BN(affine)+ReLU applied during staging.
// 256 threads = 4 waves; 64 rows/block; wave w owns rows w*16..w*16+15, all 128 cols.

template<int MODE>
__launch_bounds__(256)
__global__ void gemm_kernel(const float* __restrict__ X, const ushort* __restrict__ WTl,
                            const float* __restrict__ bnacc, const float* __restrict__ gamma,
                            const float* __restrict__ beta, const float* __restrict__ dinv,
                            ushort* __restrict__ H, int N) {
    __shared__ uint4 xs4[64 * 16];    // 16 KB: 64 rows x 16 chunks of 8 bf16, swizzled
    __shared__ uint4 wt4[128 * 16];   // 32 KB: WT[n][k], swizzled
    int t = threadIdx.x;
    int kc = t & 15;                  // 16B chunk index along K (features kc*8..kc*8+7)
    int row0 = blockIdx.x * 64;

    float sc[8], sh[8];
    if (MODE) {
        const float invN = 1.0f / (float)NN;
        #pragma unroll
        for (int j = 0; j < 8; j++) {
            int f = kc * 8 + j;
            float mean = bnacc[f] * invN;
            float var = bnacc[128 + f] * invN - mean * mean;
            float s = gamma[f] * rsqrtf(var + BN_EPS);
            sc[j] = s;
            sh[j] = beta[f] - mean * s;
        }
    }

    // stage X rows (f32 -> bf16, optional BN+ReLU)
    const float4* X4 = (const float4*)X;
    #pragma unroll
    for (int i = 0; i < 4; i++) {
        int row = (t >> 4) + i * 16;
        int r = row0 + row;
        float v[8];
        if (r < N) {
            float4 a = X4[(size_t)r * 32 + kc * 2];
            float4 b = X4[(size_t)r * 32 + kc * 2 + 1];
            v[0] = a.x; v[1] = a.y; v[2] = a.z; v[3] = a.w;
            v[4] = b.x; v[5] = b.y; v[6] = b.z; v[7] = b.w;
            if (MODE) {
                #pragma unroll
                for (int j = 0; j < 8; j++) v[j] = fmaxf(v[j] * sc[j] + sh[j], 0.f);
            }
        } else {
            #pragma unroll
            for (int j = 0; j < 8; j++) v[j] = 0.f;
        }
        uint4 p;
        p.x = (uint)f2bf(v[0]) | ((uint)f2bf(v[1]) << 16);
        p.y = (uint)f2bf(v[2]) | ((uint)f2bf(v[3]) << 16);
        p.z = (uint)f2bf(v[4]) | ((uint)f2bf(v[5]) << 16);
        p.w = (uint)f2bf(v[6]) | ((uint)f2bf(v[7]) << 16);
        xs4[row * 16 + (kc ^ (row & 7))] = p;
    }
    // stage WT (already bf16)
    const uint4* WT4 = (const uint4*)WTl;
    #pragma unroll
    for (int i = 0; i < 8; i++) {
        int n = (t >> 4) + i * 16;
        wt4[n * 16 + (kc ^ (n & 7))] = WT4[n * 16 + kc];
    }
    __syncthreads();

    int w = t >> 6, l = t & 63;
    int l16 = l >> 4;                 // 0..3
    int lrow = w * 16 + (l & 15);     // A row within block
    f32x4 acc[8];
    #pragma unroll
    for (int c = 0; c < 8; c++) acc[c] = (f32x4){0.f, 0.f, 0.f, 0.f};

    #pragma unroll
    for (int ks = 0; ks < 4; ks++) {
        int kk = ks * 4 + l16;        // chunk index along K for this lane
        uint4 av = xs4[lrow * 16 + (kk ^ (lrow & 7))];
        short8 a = *(short8*)&av;
        #pragma unroll
        for (int c = 0; c < 8; c++) {
            int n = c * 16 + (l & 15);
            uint4 bv = wt4[n * 16 + (kk ^ (n & 7))];
            short8 b = *(short8*)&bv;
            acc[c] = __builtin_amdgcn_mfma_f32_16x16x32_bf16(a, b, acc[c], 0, 0, 0);
        }
    }

    // epilogue: C row = w*16 + l16*4 + j, col = c*16 + (l&15); scale by dinv, store bf16
    #pragma unroll
    for (int j = 0; j < 4; j++) {
        int grow = row0 + w * 16 + l16 * 4 + j;
        if (grow < N) {
            float dv = dinv[grow];
            #pragma unroll
            for (int c = 0; c < 8; c++) {
                H[(size_t)grow * DH + c * 16 + (l & 15)] = f2bf(acc[c][j] * dv);
            }
        }
    }
}

// ---------------- Aggregation: out[n] = dinv[n]*(sum_e H'[src_e] + H'[n]) + b ----------------

__device__ __forceinline__ float bf_lo(uint v) { return __uint_as_float(v << 16); }
__device__ __forceinline__ float bf_hi(uint v) { return __uint_as_float(v & 0xffff0000u); }

__launch_bounds__(256)
__global__ void agg_kernel(const uint* __restrict__ H, const int* __restrict__ offsets,
                           const int* __restrict__ csr_src, const float* __restrict__ dinv,
                           const float* __restrict__ bias, float* __restrict__ out, int N) {
    int n = blockIdx.x * 4 + (threadIdx.x >> 6);
    int lane = threadIdx.x & 63;
    if (n >= N) return;
    int beg = offsets[n], end = offsets[n + 1];
    float ax = 0.f, ay = 0.f;
    int e = beg;
    for (; e + 3 < end; e += 4) {
        int s0 = csr_src[e];
        int s1 = csr_src[e + 1];
        int s2 = csr_src[e + 2];
        int s3 = csr_src[e + 3];
        uint v0 = H[(size_t)s0 * 64 + lane];
        uint v1 = H[(size_t)s1 * 64 + lane];
        uint v2 = H[(size_t)s2 * 64 + lane];
        uint v3 = H[(size_t)s3 * 64 + lane];
        ax += bf_lo(v0) + bf_lo(v1) + bf_lo(v2) + bf_lo(v3);
        ay += bf_hi(v0) + bf_hi(v1) + bf_hi(v2) + bf_hi(v3);
    }
    for (; e < end; e++) {
        uint v = H[(size_t)csr_src[e] * 64 + lane];
        ax += bf_lo(v);
        ay += bf_hi(v);
    }
    uint vn = H[(size_t)n * 64 + lane];
    ax += bf_lo(vn);
    ay += bf_hi(vn);
    float dv = dinv[n];
    float2 b = ((const float2*)bias)[lane];
    ((float2*)out)[(size_t)n * 64 + lane] = make_float2(ax * dv + b.x, ay * dv + b.y);
}

// ---------------- BatchNorm stats (sum, sumsq per feature) ----------------

__launch_bounds__(256)
__global__ void bnstats_kernel(const float* __restrict__ A, float* __restrict__ acc, int N) {
    int f = threadIdx.x & 127;
    int rh = threadIdx.x >> 7;
    float s = 0.f, sq = 0.f;
    for (int r = blockIdx.x * 2 + rh; r < N; r += gridDim.x * 2) {
        float v = A[(size_t)r * DH + f];
        s += v;
        sq += v * v;
    }
    __shared__ float ls[256], lq[256];
    ls[threadIdx.x] = s;
    lq[threadIdx.x] = sq;
    __syncthreads();
    if (threadIdx.x < 128) {
        atomicAdd(&acc[f], ls[threadIdx.x] + ls[threadIdx.x + 128]);
        atomicAdd(&acc[128 + f], lq[threadIdx.x] + lq[threadIdx.x + 128]);
    }
}

// ---------------- Pooling with fused BN+ReLU ----------------

__device__ __forceinline__ int lower_bound_dev(const int* __restrict__ a, int n, int key) {
    int lo = 0, hi = n;
    while (lo < hi) {
        int m = (lo + hi) >> 1;
        if (a[m] < key) lo = m + 1; else hi = m;
    }
    return lo;
}

__launch_bounds__(256)
__global__ void pool_kernel(const float* __restrict__ AGG, const int* __restrict__ batch,
                            const float* __restrict__ bnacc, const float* __restrict__ gamma,
                            const float* __restrict__ beta, float* __restrict__ pooled, int N) {
    int g = blockIdx.x;
    __shared__ int sbeg, send;
    if (threadIdx.x == 0) {
        sbeg = lower_bound_dev(batch, N, g);
        send = lower_bound_dev(batch, N, g + 1);
    }
    __syncthreads();
    int beg = sbeg, end = send;
    int f = threadIdx.x & 127;
    int rh = threadIdx.x >> 7;
    const float invN = 1.0f / (float)NN;
    float mean = bnacc[f] * invN;
    float var = bnacc[128 + f] * invN - mean * mean;
    float sc = gamma[f] * rsqrtf(var + BN_EPS);
    float shf = beta[f] - mean * sc;
    float s = 0.f;
    for (int r = beg + rh; r < end; r += 2)
        s += fmaxf(AGG[(size_t)r * DH + f] * sc + shf, 0.f);
    __shared__ float ls[256];
    ls[threadIdx.x] = s;
    __syncthreads();
    if (threadIdx.x < 128) {
        float tot = ls[threadIdx.x] + ls[threadIdx.x + 128];
        float cnt = (float)(end - beg);
        pooled[g * DH + f] = tot / fmaxf(cnt, 1.f);
    }
}

// ---------------- Final linear: out = pooled @ Wl + bl ----------------

__launch_bounds__(256)
__global__ void final_kernel(const float* __restrict__ pooled, const float* __restrict__ Wl,
                             const float* __restrict__ bl, float* __restrict__ out) {
    int gid = blockIdx.x * blockDim.x + threadIdx.x;
    if (gid >= NGRAPH * NCLS) return;
    int g = gid / NCLS, c = gid % NCLS;
    float s = bl[c];
    #pragma unroll 8
    for (int k = 0; k < DH; k++) s += pooled[g * DH + k] * Wl[k * NCLS + c];
    out[gid] = s;
}

// ---------------- Launch ----------------

extern "C" void kernel_launch(void* const* d_in, const int* in_sizes, int n_in,
                              void* d_out, int out_size, void* d_ws, size_t ws_size,
                              hipStream_t stream) {
    const float* x     = (const float*)d_in[0];
    const int*   edges = (const int*)d_in[1];
    const int*   batch = (const int*)d_in[2];
    const float* W1    = (const float*)d_in[3];
    const float* b1    = (const float*)d_in[4];
    const float* g1    = (const float*)d_in[5];
    const float* be1   = (const float*)d_in[6];
    const float* Wc    = (const float*)d_in[7];
    const float* bc    = (const float*)d_in[8];
    const float* gc    = (const float*)d_in[9];
    const float* bec   = (const float*)d_in[10];
    const float* Wl    = (const float*)d_in[11];
    const float* bl    = (const float*)d_in[12];
    float* out = (float*)d_out;

    const int* esrc = edges;
    const int* edst = edges + NE;

    char* w = (char*)d_ws;
    auto alloc = [&](size_t bytes) -> void* {
        void* p = (void*)w;
        w += (bytes + 255) & ~(size_t)255;
        return p;
    };
    int*    counts  = (int*)alloc(NN * 4);
    int*    offsets = (int*)alloc((NN + 1) * 4);
    int*    cursor  = (int*)alloc(NN * 4);
    float*  dinv    = (float*)alloc(NN * 4);
    int*    csr_src = (int*)alloc(NE * 4);
    int*    bsum    = (int*)alloc(256 * 4);
    float*  bn_acc  = (float*)alloc(4 * 256 * 4);   // per-layer {sum[128], sumsq[128]}
    float*  pooled  = (float*)alloc(NGRAPH * DH * 4);
    ushort* WT      = (ushort*)alloc(4 * DH * DH * 2);       // bf16 W^T per layer
    uint*   H       = (uint*)alloc((size_t)NN * 64 * 4);     // bf16-packed [N,128]
    float*  AGG     = (float*)alloc((size_t)NN * DH * 4);

    hipMemsetAsync(counts, 0, NN * 4, stream);
    hipMemsetAsync(bn_acc, 0, 4 * 256 * 4, stream);
    hist_kernel<<<(NE + 255) / 256, 256, 0, stream>>>(edst, counts, NE);
    compute_dinv_kernel<<<(NN + 255) / 256, 256, 0, stream>>>(counts, dinv, NN);
    scan1_kernel<<<SCAN_NB, 256, 0, stream>>>(counts, bsum, NN);
    scan2_kernel<<<1, 256, 0, stream>>>(bsum, SCAN_NB);
    scan3_kernel<<<SCAN_NB, 256, 0, stream>>>(counts, bsum, offsets, cursor, NN);
    fill_kernel<<<(NE + 255) / 256, 256, 0, stream>>>(esrc, edst, cursor, csr_src, NE);
    wtrans_kernel<<<64, 256, 0, stream>>>(W1, Wc, WT);

    const float* act = x;
    for (int l = 0; l < 4; l++) {
        const float* bm  = (l == 0) ? b1 : bc + (size_t)(l - 1) * DH;
        const float* gp  = (l == 1) ? g1 : gc + (size_t)(l - 2) * DH;
        const float* bep = (l == 1) ? be1 : bec + (size_t)(l - 2) * DH;
        const ushort* WTl = WT + (size_t)l * DH * DH;

        if (l == 0) {
            gemm_kernel<0><<<GEMM_NB, 256, 0, stream>>>(
                act, WTl, nullptr, nullptr, nullptr, dinv, (ushort*)H, NN);
        } else {
            gemm_kernel<1><<<GEMM_NB, 256, 0, stream>>>(
                act, WTl, bn_acc + (size_t)(l - 1) * 256, gp, bep, dinv, (ushort*)H, NN);
        }
        agg_kernel<<<(NN + 3) / 4, 256, 0, stream>>>(H, offsets, csr_src, dinv, bm, AGG, NN);
        bnstats_kernel<<<256, 256, 0, stream>>>(AGG, bn_acc + (size_t)l * 256, NN);
        act = AGG;
    }

    pool_kernel<<<NGRAPH, 256, 0, stream>>>(AGG, batch, bn_acc + 3 * 256,
                                            gc + 2 * DH, bec + 2 * DH, pooled, NN);
    final_kernel<<<(NGRAPH * NCLS + 255) / 256, 256, 0, stream>>>(pooled, Wl, bl, out);
}